// Round 9
// baseline (243.495 us; speedup 1.0000x reference)
//
#include <hip/hip_runtime.h>

// SoftDTW: B=64, N=512, M=512, DIM=64, GAMMA=1.0, BANDWIDTH=0, BIG=1e10
constexpr int Bc   = 64;
constexpr int Nc   = 512;
constexpr int Mc   = 512;
constexpr int DIMc = 64;
constexpr float BIGc = 1e10f;
constexpr int CELLS = Nc * Mc;          // 1 MiB/batch row-major D (prescaled by log2e)
constexpr float LOG2E = 1.442695041f;
constexpr float LN2   = 0.6931471806f;

// kernel-B LDS geometry (dynamic, 132 KiB total)
// STRIDE=65: slot s row r -> word 65s+r. 65>=64 rows => NO (s,63)/(s+1,0)
// collision (the round-7/8 bug with STRIDE=63); odd stride => reads 2-way
// bank-aliased (free, m136), writes <=2-way.
constexpr int STRIDE   = 65;                   // words per step-slot
constexpr int SBUF     = 32 * STRIDE;          // 2080 words per stage buffer
constexpr int WAVE_LDS = 2 * SBUF;             // double-buffered per wave
constexpr int RING_OFF = 8 * WAVE_LDS;         // 33280 words
constexpr int LDS_WORDS = RING_OFF + 8 * 64;   // 33792 words = 135168 B

struct TrueC  { static constexpr bool value = true;  };
struct FalseC { static constexpr bool value = false; };

// lane l <- lane l-1 across the 64-lane wave; lane 0 <- old
__device__ __forceinline__ float dpp_shr1_f(float v, float old) {
    return __builtin_bit_cast(float, __builtin_amdgcn_update_dpp(
        __builtin_bit_cast(int, old), __builtin_bit_cast(int, v), 0x138, 0xF, 0xF, false));
}
__device__ __forceinline__ float f4c(const float4 v, int c) {
    switch (c & 3) { case 0: return v.x; case 1: return v.y;
                     case 2: return v.z; default: return v.w; }
}
__device__ __forceinline__ void f4set(float4& d, int c, float v) {
    switch (c & 3) { case 0: d.x = v; break; case 1: d.y = v; break;
                     case 2: d.z = v; break; default: d.w = v; }
}

// ---------------- Kernel A: D[b][n][m] = ||X[b,n]-Y[b,m]||^2 * log2e, row-major ---
__global__ __launch_bounds__(256)
void compute_D(const float* __restrict__ X, const float* __restrict__ Y,
               float* __restrict__ Dc)
{
    const int b   = blockIdx.x;
    const int nt  = blockIdx.y;
    const int tid = threadIdx.x;
    const int ty  = tid >> 4, tx = tid & 15;

    __shared__ float Xs[DIMc][68];       // [dim][row], padded
    __shared__ float Ys[DIMc][68];

    const float* Xb = X + ((size_t)b * Nc + (size_t)nt * 64) * DIMc;
    const float* Yb = Y + (size_t)b * Mc * DIMc;
    float*       Db = Dc + (size_t)b * CELLS;
    const int n0 = nt * 64;

    {
        const float4* Xb4 = reinterpret_cast<const float4*>(Xb);
        for (int c4 = tid; c4 < 64 * DIMc / 4; c4 += 256) {
            float4 v = Xb4[c4];
            const int n = c4 >> 4, k0 = (c4 & 15) * 4;
            Xs[k0+0][n] = v.x; Xs[k0+1][n] = v.y; Xs[k0+2][n] = v.z; Xs[k0+3][n] = v.w;
        }
    }

    for (int mt = 0; mt < Mc / 64; ++mt) {
        __syncthreads();
        {
            const float4* Yb4 = reinterpret_cast<const float4*>(Yb + (size_t)mt * 64 * DIMc);
            for (int c4 = tid; c4 < 64 * DIMc / 4; c4 += 256) {
                float4 v = Yb4[c4];
                const int n = c4 >> 4, k0 = (c4 & 15) * 4;
                Ys[k0+0][n] = v.x; Ys[k0+1][n] = v.y; Ys[k0+2][n] = v.z; Ys[k0+3][n] = v.w;
            }
        }
        __syncthreads();

        float acc[4][4];
        #pragma unroll
        for (int r = 0; r < 4; ++r)
            #pragma unroll
            for (int cc = 0; cc < 4; ++cc) acc[r][cc] = 0.f;

        #pragma unroll 8
        for (int k = 0; k < DIMc; ++k) {
            float4 xv = *reinterpret_cast<const float4*>(&Xs[k][ty * 4]);
            float4 yv = *reinterpret_cast<const float4*>(&Ys[k][tx * 4]);
            float xr[4] = {xv.x, xv.y, xv.z, xv.w};
            float yr[4] = {yv.x, yv.y, yv.z, yv.w};
            #pragma unroll
            for (int r = 0; r < 4; ++r)
                #pragma unroll
                for (int cc = 0; cc < 4; ++cc) {
                    float d = xr[r] - yr[cc];
                    acc[r][cc] = fmaf(d, d, acc[r][cc]);
                }
        }

        #pragma unroll
        for (int r = 0; r < 4; ++r) {
            const int n = n0 + ty * 4 + r;
            float4 st = make_float4(acc[r][0]*LOG2E, acc[r][1]*LOG2E,
                                    acc[r][2]*LOG2E, acc[r][3]*LOG2E);
            *reinterpret_cast<float4*>(&Db[(size_t)n * Mc + mt * 64 + tx * 4]) = st;
        }
    }
}

// ---------------- Kernel B: 8-wave systolic, ALL windows LDS-staged --------------
// Wave W owns rows r = 64W..64W+63. Every window's D parallelogram is staged
// via coalesced global->reg->LDS transpose (T14: loads issued before the body,
// LDS writes after). Out-of-diag-range staged values are garbage-but-in-slab and
// masked in the slow body; the single possible slab overrun (W=7,q=31,lane63,u7)
// takes a 3-scalar patch load. Neighbor via DPP wave_shr:1; wave boundary via
// 2-parity LDS ring written as b128 from packed regs. One raw s_barrier per
// window (lgkm drain only; global loads stay in flight).
__global__ __launch_bounds__(512)
void softdtw_sys8(const float* __restrict__ Dc, const int* __restrict__ lengths,
                  float* __restrict__ out)
{
    extern __shared__ float lds[];
    const int b    = blockIdx.x;
    const int t    = threadIdx.x;
    const int lane = t & 63;
    const int W    = __builtin_amdgcn_readfirstlane(t >> 6);   // scalar 0..7
    const int L    = lengths[b];
    const int r    = (W << 6) + lane;       // 0-based row
    const int i    = r + 1;
    const float* Dbat = Dc + (size_t)b * CELLS;

    float* stageW = lds + W * WAVE_LDS;

    if (t < 64) lds[RING_OFF + t] = BIGc;   // ring[0] (no writer)
    __syncthreads();

    const bool l0   = (lane == 0);
    const bool iok  = (i <= L);
    const int  gcap = (i == L) ? (L + 510) : -1;   // diag of cell (L, 512)
    const int  qcap = (L + 510) >> 5;
    const bool rowsOK = ((W << 6) + 64) <= L;
    const int  qf = (W == 0) ? 0 : (2 * W - 1);    // warm-up window first
    const int  ql = 2 * W + 17;

    float own = BIGc, nb1 = BIGc, nb2 = BIGc, res = 0.f;
    if (W == 0 && l0) nb2 = 0.f;            // R[0][0] seed

    // per-lane constant address pieces
    const int lbase = (((W << 6) + (lane >> 3)) * 511) + ((lane & 7) << 2); // stage loads
    const int wbw   = ((lane & 7) << 2) * STRIDE + (lane >> 3);             // stage writes

    // stage loads: rows rr = 64W+(lane>>3)+8u, diagonals g = 32qn+(lane&7)*4..+3
    auto stageLoad = [&](int qn, float4* sreg) {
        const int gb = qn * 32;
        #pragma unroll
        for (int u = 0; u < 8; ++u) {
            const int idx = lbase + u * (8 * 511) + gb;
            if (idx <= CELLS - 4) {
                sreg[u] = *reinterpret_cast<const float4*>(Dbat + idx);
            } else {
                // only (W=7,u=7,lane=63,qn=31): g=1020..1022 exact, g=1023 invalid
                sreg[u] = make_float4(Dbat[CELLS-3], Dbat[CELLS-2], Dbat[CELLS-1], 0.f);
            }
        }
    };
    auto stageWrite = [&](int qn, const float4* sreg) {
        float* wb = stageW + (qn & 1) * SBUF + wbw;
        #pragma unroll
        for (int u = 0; u < 8; ++u) {
            wb[0 * STRIDE + u * 8] = sreg[u].x;
            wb[1 * STRIDE + u * 8] = sreg[u].y;
            wb[2 * STRIDE + u * 8] = sreg[u].z;
            wb[3 * STRIDE + u * 8] = sreg[u].w;
        }
    };

    {   // prologue: stage first window
        float4 s0[8];
        stageLoad(qf, s0);
        stageWrite(qf, s0);
    }

    for (int c = 0; c < 39; ++c) {
        const int q = c - W;
        if (q >= qf && q <= ql) {
            const int g0 = q * 32;

            // ring window in (uniform broadcast b128 reads, off the chain)
            float4 rv[8];
            {
                const float4* rp = reinterpret_cast<const float4*>(
                    lds + RING_OFF + W * 64 + (g0 & 63));
                #pragma unroll
                for (int u = 0; u < 8; ++u) rv[u] = rp[u];
            }

            // issue next-window stage loads EARLY (coalesced, always)
            const bool doNext = (q + 1 <= ql);
            float4 sreg[8];
            if (doNext) stageLoad(q + 1, sreg);

            const float* rb = stageW + (q & 1) * SBUF + lane;
            float4 expv[8];                 // packed boundary values for ring export

            const bool fastC = rowsOK && q >= 2*W+2 && q <= 2*W+15 && q != qcap;

            auto body = [&](auto FASTC) {
                constexpr bool FAST = decltype(FASTC)::value;
                #pragma unroll
                for (int s = 0; s < 32; ++s) {
                    const int g = g0 + s;
                    const float mn = fminf(nb2, fminf(nb1, own));
                    const float e  = __builtin_amdgcn_exp2f(mn - nb2)
                                   + __builtin_amdgcn_exp2f(mn - nb1)
                                   + __builtin_amdgcn_exp2f(mn - own);
                    const float sm = mn - __builtin_amdgcn_logf(e);   // log2
                    float v = rb[s * STRIDE] + sm;
                    if (!FAST) {
                        const bool jok = (unsigned)(g - r) < (unsigned)Mc;
                        v = (jok && iok) ? v : BIGc;
                        res = (g == gcap) ? v : res;   // capture (always slow window)
                    }
                    f4set(expv[s >> 2], s, v);
                    const float sh = dpp_shr1_f(v, BIGc);
                    nb2 = nb1;
                    nb1 = l0 ? f4c(rv[s >> 2], s) : sh;
                    own = v;
                }
            };
            if (fastC) body(TrueC{}); else body(FalseC{});

            // LDS-write the staged tile LATE (global latency hidden under body)
            if (doNext) stageWrite(q + 1, sreg);

            // ring export: 8x b128 from packed regs (lane 63 only)
            if (W < 7 && lane == 63) {
                float* re = lds + RING_OFF + (W + 1) * 64 + (g0 & 63);
                #pragma unroll
                for (int u = 0; u < 8; ++u)
                    reinterpret_cast<float4*>(re)[u] = expv[u];
            }
        }
        asm volatile("s_waitcnt lgkmcnt(0)" ::: "memory");  // ring/stage writes visible
        __builtin_amdgcn_s_barrier();                       // no vmcnt drain
        asm volatile("" ::: "memory");
    }

    if (i == L) out[b] = res * LN2;
}

// ---------------- Fallback (no workspace): fused on-the-fly D --------------------
__global__ __launch_bounds__(512)
void softdtw_fused(const float* __restrict__ X, const float* __restrict__ Y,
                   const int* __restrict__ lengths, float* __restrict__ out)
{
    const int b = blockIdx.x;
    const int t = threadIdx.x;
    const int i = t + 1;
    const int L = lengths[b];

    __shared__ float diag[3][Nc + 1];
    for (int c = t; c <= Nc; c += 512) {
        diag[0][c] = (c == 0) ? 0.f : BIGc;
        diag[1][c] = BIGc;
    }
    float xr[DIMc];
    const float* Xrow = X + ((size_t)b * Nc + t) * DIMc;
    #pragma unroll
    for (int d = 0; d < DIMc; d += 4) {
        float4 v = *reinterpret_cast<const float4*>(Xrow + d);
        xr[d] = v.x; xr[d+1] = v.y; xr[d+2] = v.z; xr[d+3] = v.w;
    }
    const float* Yb = Y + (size_t)b * Mc * DIMc;
    __syncthreads();

    float result = BIGc;
    int cur = 2, p1 = 1, p2 = 0;
    for (int k = 2; k <= Nc + Mc; ++k) {
        const int j = k - i;
        const bool valid = (j >= 1) && (j <= Mc) && (i <= L);
        float Dval = 0.f;
        if (valid) {
            const float* Yrow = Yb + (size_t)(j - 1) * DIMc;
            float s = 0.f;
            #pragma unroll
            for (int d = 0; d < DIMc; d += 4) {
                float4 v = *reinterpret_cast<const float4*>(Yrow + d);
                float d0 = xr[d] - v.x, d1 = xr[d+1] - v.y;
                float d2 = xr[d+2] - v.z, d3 = xr[d+3] - v.w;
                s = fmaf(d0,d0,s); s = fmaf(d1,d1,s); s = fmaf(d2,d2,s); s = fmaf(d3,d3,s);
            }
            Dval = s;
        }
        const float a2 = diag[p2][i-1], a1 = diag[p1][i-1], a0 = diag[p1][i];
        const float mn = fminf(a2, fminf(a1, a0));
        const float sm = mn - __logf(__expf(mn-a2) + __expf(mn-a1) + __expf(mn-a0));
        const float val = valid ? (Dval + sm) : BIGc;
        diag[cur][i] = val;
        if (t == 0) diag[cur][0] = BIGc;
        if (k == L + Mc && i == L) result = val;
        __syncthreads();
        const int tmp = p2; p2 = p1; p1 = cur; cur = tmp;
    }
    if (i == L) out[b] = result;
}

extern "C" void kernel_launch(void* const* d_in, const int* in_sizes, int n_in,
                              void* d_out, int out_size, void* d_ws, size_t ws_size,
                              hipStream_t stream) {
    const float* X = (const float*)d_in[0];
    const float* Y = (const float*)d_in[1];
    const int* lengths = (const int*)d_in[2];
    float* out = (float*)d_out;

    const size_t need = (size_t)Bc * CELLS * sizeof(float);   // 64 MiB
    if (ws_size >= need) {
        float* Dc = (float*)d_ws;
        compute_D<<<dim3(Bc, Nc / 64), 256, 0, stream>>>(X, Y, Dc);
        softdtw_sys8<<<Bc, 512, LDS_WORDS * 4, stream>>>(Dc, lengths, out);
    } else {
        softdtw_fused<<<Bc, 512, 0, stream>>>(X, Y, lengths, out);
    }
}

// Round 10
// 219.842 us; speedup vs baseline: 1.1076x; 1.1076x over previous
//
#include <hip/hip_runtime.h>

// SoftDTW: B=64, N=512, M=512, DIM=64, GAMMA=1.0, BANDWIDTH=0, BIG=1e10
constexpr int Bc   = 64;
constexpr int Nc   = 512;
constexpr int Mc   = 512;
constexpr int DIMc = 64;
constexpr float BIGc = 1e10f;
constexpr int CELLS = Nc * Mc;          // 1 MiB/batch row-major D (prescaled by log2e)
constexpr float LOG2E = 1.442695041f;
constexpr float LN2   = 0.6931471806f;

// kernel-B LDS geometry (dynamic, 132 KiB total)
// STRIDE=65: slot s row r -> word 65s+r (no (s,63)/(s+1,0) collision; odd stride
// => b32 reads 2-way bank-aliased = free, writes <=2-way).
constexpr int STRIDE   = 65;                   // words per step-slot
constexpr int SBUF     = 32 * STRIDE;          // 2080 words per stage buffer
constexpr int WAVE_LDS = 2 * SBUF;             // double-buffered per wave
constexpr int RING_OFF = 8 * WAVE_LDS;         // 33280 words
constexpr int LDS_WORDS = RING_OFF + 8 * 64;   // 33792 words = 135168 B

struct TrueC  { static constexpr bool value = true;  };
struct FalseC { static constexpr bool value = false; };

// lane l <- lane l-1 across the 64-lane wave; lane 0 <- old
__device__ __forceinline__ float dpp_shr1_f(float v, float old) {
    return __builtin_bit_cast(float, __builtin_amdgcn_update_dpp(
        __builtin_bit_cast(int, old), __builtin_bit_cast(int, v), 0x138, 0xF, 0xF, false));
}
__device__ __forceinline__ float f4c(const float4 v, int c) {
    switch (c & 3) { case 0: return v.x; case 1: return v.y;
                     case 2: return v.z; default: return v.w; }
}
__device__ __forceinline__ void f4set(float4& d, int c, float v) {
    switch (c & 3) { case 0: d.x = v; break; case 1: d.y = v; break;
                     case 2: d.z = v; break; default: d.w = v; }
}

// ---------------- Kernel A: D[b][n][m] = ||X[b,n]-Y[b,m]||^2 * log2e, row-major ---
__global__ __launch_bounds__(256)
void compute_D(const float* __restrict__ X, const float* __restrict__ Y,
               float* __restrict__ Dc)
{
    const int b   = blockIdx.x;
    const int nt  = blockIdx.y;
    const int tid = threadIdx.x;
    const int ty  = tid >> 4, tx = tid & 15;

    __shared__ float Xs[DIMc][68];       // [dim][row], padded
    __shared__ float Ys[DIMc][68];

    const float* Xb = X + ((size_t)b * Nc + (size_t)nt * 64) * DIMc;
    const float* Yb = Y + (size_t)b * Mc * DIMc;
    float*       Db = Dc + (size_t)b * CELLS;
    const int n0 = nt * 64;

    {
        const float4* Xb4 = reinterpret_cast<const float4*>(Xb);
        for (int c4 = tid; c4 < 64 * DIMc / 4; c4 += 256) {
            float4 v = Xb4[c4];
            const int n = c4 >> 4, k0 = (c4 & 15) * 4;
            Xs[k0+0][n] = v.x; Xs[k0+1][n] = v.y; Xs[k0+2][n] = v.z; Xs[k0+3][n] = v.w;
        }
    }

    for (int mt = 0; mt < Mc / 64; ++mt) {
        __syncthreads();
        {
            const float4* Yb4 = reinterpret_cast<const float4*>(Yb + (size_t)mt * 64 * DIMc);
            for (int c4 = tid; c4 < 64 * DIMc / 4; c4 += 256) {
                float4 v = Yb4[c4];
                const int n = c4 >> 4, k0 = (c4 & 15) * 4;
                Ys[k0+0][n] = v.x; Ys[k0+1][n] = v.y; Ys[k0+2][n] = v.z; Ys[k0+3][n] = v.w;
            }
        }
        __syncthreads();

        float acc[4][4];
        #pragma unroll
        for (int r = 0; r < 4; ++r)
            #pragma unroll
            for (int cc = 0; cc < 4; ++cc) acc[r][cc] = 0.f;

        #pragma unroll 8
        for (int k = 0; k < DIMc; ++k) {
            float4 xv = *reinterpret_cast<const float4*>(&Xs[k][ty * 4]);
            float4 yv = *reinterpret_cast<const float4*>(&Ys[k][tx * 4]);
            float xr[4] = {xv.x, xv.y, xv.z, xv.w};
            float yr[4] = {yv.x, yv.y, yv.z, yv.w};
            #pragma unroll
            for (int r = 0; r < 4; ++r)
                #pragma unroll
                for (int cc = 0; cc < 4; ++cc) {
                    float d = xr[r] - yr[cc];
                    acc[r][cc] = fmaf(d, d, acc[r][cc]);
                }
        }

        #pragma unroll
        for (int r = 0; r < 4; ++r) {
            const int n = n0 + ty * 4 + r;
            float4 st = make_float4(acc[r][0]*LOG2E, acc[r][1]*LOG2E,
                                    acc[r][2]*LOG2E, acc[r][3]*LOG2E);
            *reinterpret_cast<float4*>(&Db[(size_t)n * Mc + mt * 64 + tx * 4]) = st;
        }
    }
}

// ---------------- Kernel B: 8-wave systolic, staged D, hoisted window reads ------
// Wave W owns rows r = 64W..64W+63. Window q (diags [32q,32q+32)) is staged via
// coalesced global->reg->LDS transpose; all 32 stage reads for the CURRENT
// window are hoisted into Dwin[32] registers at window start (single batched
// lgkm wait) so the 32-step body is pure VALU+DPP. The old warm-up window is
// replaced by a 2-word ring preload (nb1/nb2). Windows are capped at
// qlL=(L+510)>>5 — diagonals past the result cell are never computed.
__global__ __launch_bounds__(512)
void softdtw_sys8(const float* __restrict__ Dc, const int* __restrict__ lengths,
                  float* __restrict__ out)
{
    extern __shared__ float lds[];
    const int b    = blockIdx.x;
    const int t    = threadIdx.x;
    const int lane = t & 63;
    const int W    = __builtin_amdgcn_readfirstlane(t >> 6);   // scalar 0..7
    const int L    = lengths[b];
    const int r    = (W << 6) + lane;       // 0-based row
    const int i    = r + 1;
    const float* Dbat = Dc + (size_t)b * CELLS;

    float* stageW = lds + W * WAVE_LDS;

    if (t < 64) lds[RING_OFF + t] = BIGc;   // ring[0] (no writer)
    __syncthreads();

    const bool l0   = (lane == 0);
    const bool iok  = (i <= L);
    const int  gcap = (i == L) ? (L + 510) : -1;   // diag of result cell
    const int  qlL  = (L + 510) >> 5;              // last needed window
    const bool rowsOK = ((W << 6) + 64) <= L;
    const int  q0 = 2 * W;                          // first real window
    const int  ql = min(2 * W + 17, qlL);           // last window for this wave
    const int  cmax = 8 + qlL;

    float own = BIGc, nb1 = BIGc, nb2 = BIGc, res = 0.f;
    if (W == 0 && l0) nb2 = 0.f;            // R[0][0] seed

    // per-lane constant address pieces
    const int lbase = (((W << 6) + (lane >> 3)) * 511) + ((lane & 7) << 2); // stage loads
    const int wbw   = ((lane & 7) << 2) * STRIDE + (lane >> 3);             // stage writes

    // stage loads: rows rr = 64W+(lane>>3)+8u, diagonals g = 32qn+(lane&7)*4..+3
    auto stageLoad = [&](int qn, float4* sreg) {
        const int gb = qn * 32;
        #pragma unroll
        for (int u = 0; u < 8; ++u) {
            const int idx = lbase + u * (8 * 511) + gb;
            if (idx <= CELLS - 4) {
                sreg[u] = *reinterpret_cast<const float4*>(Dbat + idx);
            } else {
                // only (W=7,u=7,lane=63,qn=31): g=1020..1022 exact, g=1023 invalid
                sreg[u] = make_float4(Dbat[CELLS-3], Dbat[CELLS-2], Dbat[CELLS-1], 0.f);
            }
        }
    };
    auto stageWrite = [&](int qn, const float4* sreg) {
        float* wb = stageW + (qn & 1) * SBUF + wbw;
        #pragma unroll
        for (int u = 0; u < 8; ++u) {
            wb[0 * STRIDE + u * 8] = sreg[u].x;
            wb[1 * STRIDE + u * 8] = sreg[u].y;
            wb[2 * STRIDE + u * 8] = sreg[u].z;
            wb[3 * STRIDE + u * 8] = sreg[u].w;
        }
    };

    {   // prologue: stage first real window q0 (parity 0)
        float4 s0[8];
        stageLoad(q0, s0);
        stageWrite(q0, s0);
    }

    for (int c = 0; c < cmax; ++c) {
        const int q = c - W;
        if (q >= q0 && q <= ql) {
            const int g0 = q * 32;

            // ring window in (uniform broadcast b128 reads, off the chain)
            float4 rv[8];
            {
                const float4* rp = reinterpret_cast<const float4*>(
                    lds + RING_OFF + W * 64 + (g0 & 63));
                #pragma unroll
                for (int u = 0; u < 8; ++u) rv[u] = rp[u];
            }

            // issue next-window stage loads EARLY (coalesced)
            const bool doNext = (q + 1 <= ql);
            float4 sreg[8];
            if (doNext) stageLoad(q + 1, sreg);

            // hoist ALL current-window stage reads (one batched lgkm drain)
            const float* rb = stageW + (q & 1) * SBUF + lane;
            float Dwin[32];
            #pragma unroll
            for (int s = 0; s < 32; ++s) Dwin[s] = rb[s * STRIDE];

            float4 expv[8];                 // packed boundary values for ring export
            const bool fastC = rowsOK && q >= q0 + 2 && q <= q0 + 15 && q != qlL;

            auto body = [&](auto FASTC) {
                constexpr bool FAST = decltype(FASTC)::value;
                #pragma unroll
                for (int s = 0; s < 32; ++s) {
                    const int g = g0 + s;
                    const float mn = fminf(nb2, fminf(nb1, own));
                    const float e  = __builtin_amdgcn_exp2f(mn - nb2)
                                   + __builtin_amdgcn_exp2f(mn - nb1)
                                   + __builtin_amdgcn_exp2f(mn - own);
                    const float sm = mn - __builtin_amdgcn_logf(e);   // log2
                    float v = Dwin[s] + sm;
                    if (!FAST) {
                        const bool jok = (unsigned)(g - r) < (unsigned)Mc;
                        v = (jok && iok) ? v : BIGc;
                        res = (g == gcap) ? v : res;   // capture (always slow window)
                    }
                    f4set(expv[s >> 2], s, v);
                    const float sh = dpp_shr1_f(v, BIGc);
                    nb2 = nb1;
                    nb1 = l0 ? f4c(rv[s >> 2], s) : sh;
                    own = v;
                }
            };
            if (fastC) body(TrueC{}); else body(FalseC{});

            // LDS-write the staged tile LATE (global latency hidden under body)
            if (doNext) stageWrite(q + 1, sreg);

            // ring export: 8x b128 from packed regs (lane 63 only)
            if (W < 7 && lane == 63) {
                float* re = lds + RING_OFF + (W + 1) * 64 + (g0 & 63);
                #pragma unroll
                for (int u = 0; u < 8; ++u)
                    reinterpret_cast<float4*>(re)[u] = expv[u];
            }
        } else if (W > 0 && q == q0 - 1) {
            // ring preload replacing the old warm-up window: after window q0-1
            // (parity 1), lane0's chain state must be nb1=ring[g=64W-1],
            // nb2=ring[64W-2] (the latter is BIG by construction).
            const float p1 = lds[RING_OFF + W * 64 + 63];
            const float p0 = lds[RING_OFF + W * 64 + 62];
            nb1 = l0 ? p1 : nb1;
            nb2 = l0 ? p0 : nb2;
        }
        asm volatile("s_waitcnt lgkmcnt(0)" ::: "memory");  // ring/stage writes visible
        __builtin_amdgcn_s_barrier();                       // no vmcnt drain
        asm volatile("" ::: "memory");
    }

    if (i == L) out[b] = res * LN2;
}

// ---------------- Fallback (no workspace): fused on-the-fly D --------------------
__global__ __launch_bounds__(512)
void softdtw_fused(const float* __restrict__ X, const float* __restrict__ Y,
                   const int* __restrict__ lengths, float* __restrict__ out)
{
    const int b = blockIdx.x;
    const int t = threadIdx.x;
    const int i = t + 1;
    const int L = lengths[b];

    __shared__ float diag[3][Nc + 1];
    for (int c = t; c <= Nc; c += 512) {
        diag[0][c] = (c == 0) ? 0.f : BIGc;
        diag[1][c] = BIGc;
    }
    float xr[DIMc];
    const float* Xrow = X + ((size_t)b * Nc + t) * DIMc;
    #pragma unroll
    for (int d = 0; d < DIMc; d += 4) {
        float4 v = *reinterpret_cast<const float4*>(Xrow + d);
        xr[d] = v.x; xr[d+1] = v.y; xr[d+2] = v.z; xr[d+3] = v.w;
    }
    const float* Yb = Y + (size_t)b * Mc * DIMc;
    __syncthreads();

    float result = BIGc;
    int cur = 2, p1 = 1, p2 = 0;
    for (int k = 2; k <= Nc + Mc; ++k) {
        const int j = k - i;
        const bool valid = (j >= 1) && (j <= Mc) && (i <= L);
        float Dval = 0.f;
        if (valid) {
            const float* Yrow = Yb + (size_t)(j - 1) * DIMc;
            float s = 0.f;
            #pragma unroll
            for (int d = 0; d < DIMc; d += 4) {
                float4 v = *reinterpret_cast<const float4*>(Yrow + d);
                float d0 = xr[d] - v.x, d1 = xr[d+1] - v.y;
                float d2 = xr[d+2] - v.z, d3 = xr[d+3] - v.w;
                s = fmaf(d0,d0,s); s = fmaf(d1,d1,s); s = fmaf(d2,d2,s); s = fmaf(d3,d3,s);
            }
            Dval = s;
        }
        const float a2 = diag[p2][i-1], a1 = diag[p1][i-1], a0 = diag[p1][i];
        const float mn = fminf(a2, fminf(a1, a0));
        const float sm = mn - __logf(__expf(mn-a2) + __expf(mn-a1) + __expf(mn-a0));
        const float val = valid ? (Dval + sm) : BIGc;
        diag[cur][i] = val;
        if (t == 0) diag[cur][0] = BIGc;
        if (k == L + Mc && i == L) result = val;
        __syncthreads();
        const int tmp = p2; p2 = p1; p1 = cur; cur = tmp;
    }
    if (i == L) out[b] = result;
}

extern "C" void kernel_launch(void* const* d_in, const int* in_sizes, int n_in,
                              void* d_out, int out_size, void* d_ws, size_t ws_size,
                              hipStream_t stream) {
    const float* X = (const float*)d_in[0];
    const float* Y = (const float*)d_in[1];
    const int* lengths = (const int*)d_in[2];
    float* out = (float*)d_out;

    const size_t need = (size_t)Bc * CELLS * sizeof(float);   // 64 MiB
    if (ws_size >= need) {
        float* Dc = (float*)d_ws;
        compute_D<<<dim3(Bc, Nc / 64), 256, 0, stream>>>(X, Y, Dc);
        softdtw_sys8<<<Bc, 512, LDS_WORDS * 4, stream>>>(Dc, lengths, out);
    } else {
        softdtw_fused<<<Bc, 512, 0, stream>>>(X, Y, lengths, out);
    }
}